// Round 8
// baseline (168.607 us; speedup 1.0000x reference)
//
#include <hip/hip_runtime.h>
#include <hip/hip_fp16.h>

// UVRenderer round 7b: quad-texel table (one cache line per pixel) with
// pack/render software-pipelined via block-role fused kernels:
//   L1: [ftab | pack chunk0]   L2: [render chunk0 | pack chunk1]   L3: render chunk1
// Pack is write-dominant, render is fetch-dominant -> complementary directions.
// Fixed dims: B=4, H=W=Ht=Wt=1024, F=40000.

#define BB    4
#define HWT   (1 << 20)
#define WMASK 1023
#define HHALF (HWT / 2)

typedef unsigned uint4_ev __attribute__((ext_vector_type(4)));

static __device__ __forceinline__ unsigned h2b(float a, float b) {
    __half2 h = __floats2half2_rn(a, b);
    return *reinterpret_cast<const unsigned*>(&h);
}
static __device__ __forceinline__ float2 h2f(unsigned u) {
    return __half22float2(*reinterpret_cast<const __half2*>(&u));
}

// ---------------- device bodies ----------------

static __device__ __forceinline__ void ftab_body(
    int f, const int* __restrict__ face_uv, const float* __restrict__ vertex_uv,
    float4* __restrict__ ftab, int F)
{
    if (f >= F) return;
    const int i0 = face_uv[f * 3 + 0];
    const int i1 = face_uv[f * 3 + 1];
    const int i2 = face_uv[f * 3 + 2];
    float4 a, b;
    a.x = vertex_uv[i0 * 2 + 0]; a.y = 1.0f - vertex_uv[i0 * 2 + 1];
    a.z = vertex_uv[i1 * 2 + 0]; a.w = 1.0f - vertex_uv[i1 * 2 + 1];
    b.x = vertex_uv[i2 * 2 + 0]; b.y = 1.0f - vertex_uv[i2 * 2 + 1];
    b.z = 0.0f; b.w = 0.0f;
    ftab[f * 2 + 0] = a;
    ftab[f * 2 + 1] = b;
}

// Packs one entry of batches [b0, b0+1]; t in [0, 2M). 32 B entries.
static __device__ __forceinline__ void pack_body(
    int t, const float* __restrict__ uvmap, unsigned* __restrict__ ptexu, int b0)
{
    const int b  = b0 + (t >> 20);
    const int hw = t & (HWT - 1);
    const int i  = (b << 20) | hw;
    const int x  = hw & WMASK;
    const int y  = hw >> 10;
    const int xr = min(x + 1, WMASK);
    const int yd = min(y + 1, WMASK);
    const float* base = uvmap + ((size_t)b * 3 << 20);
    const int iTL = (y  << 10) | x,  iTR = (y  << 10) | xr;
    const int iBL = (yd << 10) | x,  iBR = (yd << 10) | xr;
    const float c0TL = base[iTL],           c0TR = base[iTR];
    const float c1TL = base[HWT + iTL],     c1TR = base[HWT + iTR];
    const float c2TL = base[2 * HWT + iTL], c2TR = base[2 * HWT + iTR];
    const float c0BL = base[iBL],           c0BR = base[iBR];
    const float c1BL = base[HWT + iBL],     c1BR = base[HWT + iBR];
    const float c2BL = base[2 * HWT + iBL], c2BR = base[2 * HWT + iBR];

    uint4_ev qa, qc;
    qa.x = h2b(c0TL, c1TL); qa.y = h2b(c2TL, c0TR); qa.z = h2b(c1TR, c2TR); qa.w = 0u;
    qc.x = h2b(c0BL, c1BL); qc.y = h2b(c2BL, c0BR); qc.z = h2b(c1BR, c2BR); qc.w = 0u;
    uint4_ev* p = reinterpret_cast<uint4_ev*>(ptexu);
    __builtin_nontemporal_store(qa, &p[(size_t)i * 2 + 0]);
    __builtin_nontemporal_store(qc, &p[(size_t)i * 2 + 1]);
}

// Renders 4 pixels of batches [b0, b0+1]; tid in [0, 512K).
static __device__ __forceinline__ void render_body(
    int tid, const unsigned* __restrict__ ptexu, const float4* __restrict__ ftab,
    const float* __restrict__ bary, const int* __restrict__ pix,
    const float* __restrict__ bkg, int F,
    float* __restrict__ render, float* __restrict__ is_valid, int b0)
{
    const float bkg0 = bkg[0], bkg1 = bkg[1], bkg2 = bkg[2];

    int idx[4], bj[4];
    #pragma unroll
    for (int j = 0; j < 4; ++j) {
        bj[j]  = b0 + (j >> 1);
        idx[j] = (bj[j] << 20) | (tid + ((j & 1) ? HHALF : 0));
    }

    int pf[4];
    #pragma unroll
    for (int j = 0; j < 4; ++j)
        pf[j] = __builtin_nontemporal_load(&pix[idx[j]]);

    float ba[4][3];
    #pragma unroll
    for (int j = 0; j < 4; ++j) {
        const size_t o = (size_t)idx[j] * 3;
        ba[j][0] = __builtin_nontemporal_load(&bary[o + 0]);
        ba[j][1] = __builtin_nontemporal_load(&bary[o + 1]);
        ba[j][2] = __builtin_nontemporal_load(&bary[o + 2]);
    }

    float4 A[4], Bv[4];
    #pragma unroll
    for (int j = 0; j < 4; ++j) {
        const int lf = (pf[j] != -1) ? pf[j] - bj[j] * F : 0;
        A[j]  = ftab[lf * 2 + 0];
        Bv[j] = ftab[lf * 2 + 1];
    }

    unsigned t0[4], t1[4], t2[4], u0[4], u1[4], u2[4];
    float wx[4], wy[4];
    #pragma unroll
    for (int j = 0; j < 4; ++j) {
        const float u = ba[j][0] * A[j].x + ba[j][1] * A[j].z + ba[j][2] * Bv[j].x;
        const float v = ba[j][0] * A[j].y + ba[j][1] * A[j].w + ba[j][2] * Bv[j].y;
        float x = fminf(fmaxf(u * 1023.0f, 0.0f), 1023.0f);
        float y = fminf(fmaxf(v * 1023.0f, 0.0f), 1023.0f);
        if (pf[j] == -1) { x = 0.0f; y = 0.0f; }
        const float xf = floorf(x), yf = floorf(y);
        wx[j] = x - xf; wy[j] = y - yf;
        const int e = (bj[j] << 20) | (((int)yf) << 10) | (int)xf;
        const uint4_ev* p = reinterpret_cast<const uint4_ev*>(ptexu);
        const uint4_ev qt = p[(size_t)e * 2 + 0];
        const uint4_ev qb = p[(size_t)e * 2 + 1];
        t0[j] = qt.x; t1[j] = qt.y; t2[j] = qt.z;
        u0[j] = qb.x; u1[j] = qb.y; u2[j] = qb.z;
    }

    #pragma unroll
    for (int j = 0; j < 4; ++j) {
        const float2 a01 = h2f(t0[j]), a2b = h2f(t1[j]), a12 = h2f(t2[j]);
        const float2 c01 = h2f(u0[j]), c2b = h2f(u1[j]), c12 = h2f(u2[j]);
        const float iwx = 1.0f - wx[j], iwy = 1.0f - wy[j];
        const float top0 = a01.x * iwx + a2b.y * wx[j];
        const float top1 = a01.y * iwx + a12.x * wx[j];
        const float top2 = a2b.x * iwx + a12.y * wx[j];
        const float bot0 = c01.x * iwx + c2b.y * wx[j];
        const float bot1 = c01.y * iwx + c12.x * wx[j];
        const float bot2 = c2b.x * iwx + c12.y * wx[j];
        float r0 = top0 * iwy + bot0 * wy[j];
        float r1 = top1 * iwy + bot1 * wy[j];
        float r2 = top2 * iwy + bot2 * wy[j];
        float vf = 1.0f;
        if (pf[j] == -1) { r0 = bkg0; r1 = bkg1; r2 = bkg2; vf = 0.0f; }
        const int hwj = idx[j] & (HWT - 1);
        const int ob  = (bj[j] * 3) << 20;
        __builtin_nontemporal_store(r0, &render[ob + hwj]);
        __builtin_nontemporal_store(r1, &render[ob + HWT + hwj]);
        __builtin_nontemporal_store(r2, &render[ob + 2 * HWT + hwj]);
        __builtin_nontemporal_store(vf, &is_valid[idx[j]]);
    }
}

// ---------------- fused-pipeline kernels (32 B entry path) ----------------

// L1: blocks [0, nftab) build ftab; blocks [nftab, nftab+8192) pack chunk 0.
__global__ __launch_bounds__(256) void k_ftab_pack0(
    const int* __restrict__ face_uv, const float* __restrict__ vertex_uv,
    float4* __restrict__ ftab, const float* __restrict__ uvmap,
    unsigned* __restrict__ ptexu, int F, int nftab)
{
    const int g = blockIdx.x;
    if (g < nftab) {
        ftab_body(g * 256 + threadIdx.x, face_uv, vertex_uv, ftab, F);
    } else {
        pack_body((g - nftab) * 256 + threadIdx.x, uvmap, ptexu, 0);
    }
}

// L2: 10240 blocks. g%5==0 -> render block of chunk 0 (2048 blocks);
//                   else   -> pack block of chunk 1 (8192 blocks).
__global__ __launch_bounds__(256) void k_mix(
    unsigned* __restrict__ ptexu, const float4* __restrict__ ftab,
    const float* __restrict__ bary, const int* __restrict__ pix,
    const float* __restrict__ bkg, int F,
    float* __restrict__ render, float* __restrict__ is_valid,
    const float* __restrict__ uvmap)
{
    const int g = blockIdx.x;
    const int r = g % 5;
    if (r == 0) {
        render_body((g / 5) * 256 + threadIdx.x, ptexu, ftab, bary, pix, bkg, F,
                    render, is_valid, 0);
    } else {
        const int pb = (g / 5) * 4 + (r - 1);
        pack_body(pb * 256 + threadIdx.x, uvmap, ptexu, 2);
    }
}

// L3: render chunk 1.
__global__ __launch_bounds__(256) void k_render1(
    const unsigned* __restrict__ ptexu, const float4* __restrict__ ftab,
    const float* __restrict__ bary, const int* __restrict__ pix,
    const float* __restrict__ bkg, int F,
    float* __restrict__ render, float* __restrict__ is_valid)
{
    render_body(blockIdx.x * 256 + threadIdx.x, ptexu, ftab, bary, pix, bkg, F,
                render, is_valid, 2);
}

// ---------------- fallbacks ----------------

__global__ __launch_bounds__(256) void build_ftab(
    const int* __restrict__ face_uv, const float* __restrict__ vertex_uv,
    float4* __restrict__ ftab, int F)
{
    ftab_body(blockIdx.x * blockDim.x + threadIdx.x, face_uv, vertex_uv, ftab, F);
}

// q24 fallback kernels (96 MiB table), serial schedule.
__global__ __launch_bounds__(256) void pack_quad24(
    const float* __restrict__ uvmap, unsigned* __restrict__ ptexu)
{
    const int t = blockIdx.x * blockDim.x + threadIdx.x;  // 4M
    const int b  = t >> 20;
    const int hw = t & (HWT - 1);
    const int x  = hw & WMASK;
    const int y  = hw >> 10;
    const int xr = min(x + 1, WMASK);
    const int yd = min(y + 1, WMASK);
    const float* base = uvmap + ((size_t)b * 3 << 20);
    const int iTL = (y  << 10) | x,  iTR = (y  << 10) | xr;
    const int iBL = (yd << 10) | x,  iBR = (yd << 10) | xr;
    const size_t o = (size_t)t * 6;
    ptexu[o + 0] = h2b(base[iTL], base[HWT + iTL]);
    ptexu[o + 1] = h2b(base[2 * HWT + iTL], base[iTR]);
    ptexu[o + 2] = h2b(base[HWT + iTR], base[2 * HWT + iTR]);
    ptexu[o + 3] = h2b(base[iBL], base[HWT + iBL]);
    ptexu[o + 4] = h2b(base[2 * HWT + iBL], base[iBR]);
    ptexu[o + 5] = h2b(base[HWT + iBR], base[2 * HWT + iBR]);
}

__global__ __launch_bounds__(256) void render_quad24(
    const unsigned* __restrict__ ptexu, const float4* __restrict__ ftab,
    const float* __restrict__ bary, const int* __restrict__ pix,
    const float* __restrict__ bkg, int F,
    float* __restrict__ render, float* __restrict__ is_valid)
{
    const int tid = blockIdx.x * blockDim.x + threadIdx.x;  // 1M, 4 px each
    const float bkg0 = bkg[0], bkg1 = bkg[1], bkg2 = bkg[2];
    #pragma unroll
    for (int j = 0; j < 4; ++j) {
        const int idx = (j << 20) | tid;
        const int pf = pix[idx];
        float r0 = bkg0, r1 = bkg1, r2 = bkg2, vf = 0.0f;
        if (pf != -1) {
            vf = 1.0f;
            const int lf = pf - j * F;
            const float4 A  = ftab[lf * 2 + 0];
            const float4 Bv = ftab[lf * 2 + 1];
            const size_t o = (size_t)idx * 3;
            const float b0 = bary[o], b1 = bary[o + 1], b2 = bary[o + 2];
            const float u = b0 * A.x + b1 * A.z + b2 * Bv.x;
            const float v = b0 * A.y + b1 * A.w + b2 * Bv.y;
            const float x = fminf(fmaxf(u * 1023.0f, 0.0f), 1023.0f);
            const float y = fminf(fmaxf(v * 1023.0f, 0.0f), 1023.0f);
            const float xf = floorf(x), yf = floorf(y);
            const float wx = x - xf, wy = y - yf;
            const size_t e = (size_t)((j << 20) | (((int)yf) << 10) | (int)xf) * 6;
            const float2 a01 = h2f(ptexu[e + 0]);
            const float2 a2b = h2f(ptexu[e + 1]);
            const float2 a12 = h2f(ptexu[e + 2]);
            const float2 c01 = h2f(ptexu[e + 3]);
            const float2 c2b = h2f(ptexu[e + 4]);
            const float2 c12 = h2f(ptexu[e + 5]);
            const float iwx = 1.0f - wx, iwy = 1.0f - wy;
            r0 = (a01.x * iwx + a2b.y * wx) * iwy + (c01.x * iwx + c2b.y * wx) * wy;
            r1 = (a01.y * iwx + a12.x * wx) * iwy + (c01.y * iwx + c12.x * wx) * wy;
            r2 = (a2b.x * iwx + a12.y * wx) * iwy + (c2b.x * iwx + c12.y * wx) * wy;
        }
        const int ob = (j * 3) << 20;
        __builtin_nontemporal_store(r0, &render[ob | tid]);
        __builtin_nontemporal_store(r1, &render[(ob + HWT) | tid]);
        __builtin_nontemporal_store(r2, &render[(ob + 2 * HWT) | tid]);
        __builtin_nontemporal_store(vf, &is_valid[(j << 20) | tid]);
    }
}

// Direct planar gather (no workspace needed at all).
__global__ __launch_bounds__(256) void uvrender_direct(
    const float* __restrict__ bary, const float* __restrict__ uvmap,
    const float* __restrict__ vertex_uv, const float* __restrict__ bkg,
    const int* __restrict__ pix_to_face, const int* __restrict__ face_uv,
    int F, float* __restrict__ render, float* __restrict__ is_valid)
{
    const int total = BB * HWT;
    const float bkg0 = bkg[0], bkg1 = bkg[1], bkg2 = bkg[2];
    for (int idx = blockIdx.x * blockDim.x + threadIdx.x; idx < total;
         idx += gridDim.x * blockDim.x) {
        const int b  = idx >> 20;
        const int hw = idx & (HWT - 1);
        const int pf = pix_to_face[idx];
        float r0 = bkg0, r1 = bkg1, r2 = bkg2, vflag = 0.0f;
        if (pf != -1) {
            vflag = 1.0f;
            const int local = pf - b * F;
            const int i0 = face_uv[local * 3 + 0];
            const int i1 = face_uv[local * 3 + 1];
            const int i2 = face_uv[local * 3 + 2];
            const float b0 = bary[(size_t)idx * 3 + 0];
            const float b1 = bary[(size_t)idx * 3 + 1];
            const float b2 = bary[(size_t)idx * 3 + 2];
            const float u = b0 * vertex_uv[i0 * 2] + b1 * vertex_uv[i1 * 2] +
                            b2 * vertex_uv[i2 * 2];
            const float v = b0 * (1.0f - vertex_uv[i0 * 2 + 1]) +
                            b1 * (1.0f - vertex_uv[i1 * 2 + 1]) +
                            b2 * (1.0f - vertex_uv[i2 * 2 + 1]);
            float x = fminf(fmaxf(u * 1023.0f, 0.0f), 1023.0f);
            float y = fminf(fmaxf(v * 1023.0f, 0.0f), 1023.0f);
            const float xf = floorf(x), yf = floorf(y);
            const int x0 = (int)xf, y0 = (int)yf;
            const int x1 = min(x0 + 1, WMASK), y1 = min(y0 + 1, WMASK);
            const float wxx = x - xf, wyy = y - yf;
            const float iwx = 1.0f - wxx, iwy = 1.0f - wyy;
            const float* texb = uvmap + ((size_t)b * 3 << 20);
            float out[3];
            #pragma unroll
            for (int c = 0; c < 3; ++c) {
                const float* t = texb + ((size_t)c << 20);
                const float t00 = t[(y0 << 10) | x0];
                const float t01 = t[(y0 << 10) | x1];
                const float t10 = t[(y1 << 10) | x0];
                const float t11 = t[(y1 << 10) | x1];
                out[c] = (t00 * iwx + t01 * wxx) * iwy + (t10 * iwx + t11 * wxx) * wyy;
            }
            r0 = out[0]; r1 = out[1]; r2 = out[2];
        }
        const size_t ob = (size_t)b * 3 * HWT + hw;
        __builtin_nontemporal_store(r0, &render[ob]);
        __builtin_nontemporal_store(r1, &render[ob + HWT]);
        __builtin_nontemporal_store(r2, &render[ob + 2 * (size_t)HWT]);
        __builtin_nontemporal_store(vflag, &is_valid[idx]);
    }
}

extern "C" void kernel_launch(void* const* d_in, const int* in_sizes, int n_in,
                              void* d_out, int out_size, void* d_ws, size_t ws_size,
                              hipStream_t stream) {
    const float* bary        = (const float*)d_in[0];
    const float* uvmap       = (const float*)d_in[1];
    const float* vertex_uv   = (const float*)d_in[2];
    const float* bkg         = (const float*)d_in[3];
    const int*   pix_to_face = (const int*)d_in[4];
    const int*   face_uv     = (const int*)d_in[5];
    const int F = in_sizes[5] / 3;   // 40000

    float* render   = (float*)d_out;
    float* is_valid = (float*)d_out + (size_t)BB * 3 * HWT;

    const size_t Q32_B  = (size_t)BB * HWT * 32;            // 128 MiB
    const size_t Q24_B  = (size_t)BB * HWT * 24;            //  96 MiB
    const size_t FTAB_B = (size_t)F * 2 * sizeof(float4);   // ~1.25 MiB

    if (ws_size >= Q32_B + FTAB_B) {
        unsigned* ptexu = (unsigned*)d_ws;
        float4*   ftab  = (float4*)((char*)d_ws + Q32_B);
        const int nftab = (F + 255) / 256;
        k_ftab_pack0<<<nftab + 8192, 256, 0, stream>>>(
            face_uv, vertex_uv, ftab, uvmap, ptexu, F, nftab);
        k_mix<<<10240, 256, 0, stream>>>(
            ptexu, ftab, bary, pix_to_face, bkg, F, render, is_valid, uvmap);
        k_render1<<<2048, 256, 0, stream>>>(
            ptexu, ftab, bary, pix_to_face, bkg, F, render, is_valid);
    } else if (ws_size >= Q24_B + FTAB_B) {
        unsigned* ptexu = (unsigned*)d_ws;
        float4*   ftab  = (float4*)((char*)d_ws + Q24_B);
        build_ftab<<<(F + 255) / 256, 256, 0, stream>>>(face_uv, vertex_uv, ftab, F);
        pack_quad24<<<(BB * HWT) / 256, 256, 0, stream>>>(uvmap, ptexu);
        render_quad24<<<HWT / 256, 256, 0, stream>>>(
            ptexu, ftab, bary, pix_to_face, bkg, F, render, is_valid);
    } else {
        uvrender_direct<<<2048, 256, 0, stream>>>(
            bary, uvmap, vertex_uv, bkg, pix_to_face, face_uv, F,
            render, is_valid);
    }
}

// Round 9
// 131.789 us; speedup vs baseline: 1.2794x; 1.2794x over previous
//
#include <hip/hip_runtime.h>
#include <hip/hip_fp16.h>

// UVRenderer round 9: best-known structure (R5) restored.
//   K1 k_ftab_pack : [ftab build | quad-table pack, all 4 batches] (block-role)
//   K2 render_quad : per-pixel: ftab lookup -> bary UV -> ONE 64B-line gather
//                    (32 B quad entry: all 4 bilinear taps) -> blend -> store
// Aggregate in gather kernels caps at ~3.4 TB/s (measured R5/R6/R8), so the
// schedule minimizes bytes in the gather phase; pack runs at streaming rate.
// Fixed dims: B=4, H=W=Ht=Wt=1024, F=40000.

#define BB    4
#define HWT   (1 << 20)
#define WMASK 1023

typedef unsigned uint4_ev __attribute__((ext_vector_type(4)));

static __device__ __forceinline__ unsigned h2b(float a, float b) {
    __half2 h = __floats2half2_rn(a, b);
    return *reinterpret_cast<const unsigned*>(&h);
}
static __device__ __forceinline__ float2 h2f(unsigned u) {
    return __half22float2(*reinterpret_cast<const __half2*>(&u));
}

static __device__ __forceinline__ void ftab_body(
    int f, const int* __restrict__ face_uv, const float* __restrict__ vertex_uv,
    float4* __restrict__ ftab, int F)
{
    if (f >= F) return;
    const int i0 = face_uv[f * 3 + 0];
    const int i1 = face_uv[f * 3 + 1];
    const int i2 = face_uv[f * 3 + 2];
    float4 a, b;
    a.x = vertex_uv[i0 * 2 + 0]; a.y = 1.0f - vertex_uv[i0 * 2 + 1];
    a.z = vertex_uv[i1 * 2 + 0]; a.w = 1.0f - vertex_uv[i1 * 2 + 1];
    b.x = vertex_uv[i2 * 2 + 0]; b.y = 1.0f - vertex_uv[i2 * 2 + 1];
    b.z = 0.0f; b.w = 0.0f;
    ftab[f * 2 + 0] = a;
    ftab[f * 2 + 1] = b;
}

// Packs one 32 B quad entry; t in [0, 4M). Plain stores (let caches hold it).
static __device__ __forceinline__ void pack_body(
    int t, const float* __restrict__ uvmap, unsigned* __restrict__ ptexu)
{
    const int b  = t >> 20;
    const int hw = t & (HWT - 1);
    const int x  = hw & WMASK;
    const int y  = hw >> 10;
    const int xr = min(x + 1, WMASK);
    const int yd = min(y + 1, WMASK);
    const float* base = uvmap + ((size_t)b * 3 << 20);
    const int iTL = (y  << 10) | x,  iTR = (y  << 10) | xr;
    const int iBL = (yd << 10) | x,  iBR = (yd << 10) | xr;
    const float c0TL = base[iTL],           c0TR = base[iTR];
    const float c1TL = base[HWT + iTL],     c1TR = base[HWT + iTR];
    const float c2TL = base[2 * HWT + iTL], c2TR = base[2 * HWT + iTR];
    const float c0BL = base[iBL],           c0BR = base[iBR];
    const float c1BL = base[HWT + iBL],     c1BR = base[HWT + iBR];
    const float c2BL = base[2 * HWT + iBL], c2BR = base[2 * HWT + iBR];

    uint4_ev qa, qc;
    qa.x = h2b(c0TL, c1TL); qa.y = h2b(c2TL, c0TR); qa.z = h2b(c1TR, c2TR); qa.w = 0u;
    qc.x = h2b(c0BL, c1BL); qc.y = h2b(c2BL, c0BR); qc.z = h2b(c1BR, c2BR); qc.w = 0u;
    uint4_ev* p = reinterpret_cast<uint4_ev*>(ptexu);
    p[(size_t)t * 2 + 0] = qa;
    p[(size_t)t * 2 + 1] = qc;
}

// K1: blocks [0,nftab) build ftab; blocks [nftab, nftab+16384) pack the table.
__global__ __launch_bounds__(256) void k_ftab_pack(
    const int* __restrict__ face_uv, const float* __restrict__ vertex_uv,
    float4* __restrict__ ftab, const float* __restrict__ uvmap,
    unsigned* __restrict__ ptexu, int F, int nftab)
{
    const int g = blockIdx.x;
    if (g < nftab) {
        ftab_body(g * 256 + threadIdx.x, face_uv, vertex_uv, ftab, F);
    } else {
        pack_body((g - nftab) * 256 + threadIdx.x, uvmap, ptexu);
    }
}

// K2: 1M threads, 4 pixels each (one per batch), phased load-all-then-compute.
__global__ __launch_bounds__(256) void render_quad(
    const unsigned* __restrict__ ptexu, const float4* __restrict__ ftab,
    const float* __restrict__ bary, const int* __restrict__ pix,
    const float* __restrict__ bkg, int F,
    float* __restrict__ render, float* __restrict__ is_valid)
{
    const int tid = blockIdx.x * blockDim.x + threadIdx.x;
    const float bkg0 = bkg[0], bkg1 = bkg[1], bkg2 = bkg[2];

    int pf[4];
    #pragma unroll
    for (int j = 0; j < 4; ++j)
        pf[j] = __builtin_nontemporal_load(&pix[(j << 20) | tid]);

    float ba[4][3];
    #pragma unroll
    for (int j = 0; j < 4; ++j) {
        const size_t o = (size_t)((j << 20) | tid) * 3;
        ba[j][0] = __builtin_nontemporal_load(&bary[o + 0]);
        ba[j][1] = __builtin_nontemporal_load(&bary[o + 1]);
        ba[j][2] = __builtin_nontemporal_load(&bary[o + 2]);
    }

    float4 A[4], Bv[4];
    #pragma unroll
    for (int j = 0; j < 4; ++j) {
        const int lf = (pf[j] != -1) ? pf[j] - j * F : 0;
        A[j]  = ftab[lf * 2 + 0];
        Bv[j] = ftab[lf * 2 + 1];
    }

    unsigned t0[4], t1[4], t2[4], u0[4], u1[4], u2[4];
    float wx[4], wy[4];
    #pragma unroll
    for (int j = 0; j < 4; ++j) {
        const float u = ba[j][0] * A[j].x + ba[j][1] * A[j].z + ba[j][2] * Bv[j].x;
        const float v = ba[j][0] * A[j].y + ba[j][1] * A[j].w + ba[j][2] * Bv[j].y;
        float x = fminf(fmaxf(u * 1023.0f, 0.0f), 1023.0f);
        float y = fminf(fmaxf(v * 1023.0f, 0.0f), 1023.0f);
        if (pf[j] == -1) { x = 0.0f; y = 0.0f; }
        const float xf = floorf(x), yf = floorf(y);
        wx[j] = x - xf; wy[j] = y - yf;
        const int e = (j << 20) | (((int)yf) << 10) | (int)xf;
        const uint4_ev* p = reinterpret_cast<const uint4_ev*>(ptexu);
        const uint4_ev qt = p[(size_t)e * 2 + 0];
        const uint4_ev qb = p[(size_t)e * 2 + 1];
        t0[j] = qt.x; t1[j] = qt.y; t2[j] = qt.z;
        u0[j] = qb.x; u1[j] = qb.y; u2[j] = qb.z;
    }

    #pragma unroll
    for (int j = 0; j < 4; ++j) {
        const float2 a01 = h2f(t0[j]), a2b = h2f(t1[j]), a12 = h2f(t2[j]);
        const float2 c01 = h2f(u0[j]), c2b = h2f(u1[j]), c12 = h2f(u2[j]);
        const float iwx = 1.0f - wx[j], iwy = 1.0f - wy[j];
        const float top0 = a01.x * iwx + a2b.y * wx[j];
        const float top1 = a01.y * iwx + a12.x * wx[j];
        const float top2 = a2b.x * iwx + a12.y * wx[j];
        const float bot0 = c01.x * iwx + c2b.y * wx[j];
        const float bot1 = c01.y * iwx + c12.x * wx[j];
        const float bot2 = c2b.x * iwx + c12.y * wx[j];
        float r0 = top0 * iwy + bot0 * wy[j];
        float r1 = top1 * iwy + bot1 * wy[j];
        float r2 = top2 * iwy + bot2 * wy[j];
        float vf = 1.0f;
        if (pf[j] == -1) { r0 = bkg0; r1 = bkg1; r2 = bkg2; vf = 0.0f; }
        const int ob = (j * 3) << 20;
        __builtin_nontemporal_store(r0, &render[ob | tid]);
        __builtin_nontemporal_store(r1, &render[(ob + HWT) | tid]);
        __builtin_nontemporal_store(r2, &render[(ob + 2 * HWT) | tid]);
        __builtin_nontemporal_store(vf, &is_valid[(j << 20) | tid]);
    }
}

// ---------- no-workspace safety fallback (direct planar gather) ----------
__global__ __launch_bounds__(256) void uvrender_direct(
    const float* __restrict__ bary, const float* __restrict__ uvmap,
    const float* __restrict__ vertex_uv, const float* __restrict__ bkg,
    const int* __restrict__ pix_to_face, const int* __restrict__ face_uv,
    int F, float* __restrict__ render, float* __restrict__ is_valid)
{
    const int total = BB * HWT;
    const float bkg0 = bkg[0], bkg1 = bkg[1], bkg2 = bkg[2];
    for (int idx = blockIdx.x * blockDim.x + threadIdx.x; idx < total;
         idx += gridDim.x * blockDim.x) {
        const int b  = idx >> 20;
        const int hw = idx & (HWT - 1);
        const int pf = pix_to_face[idx];
        float r0 = bkg0, r1 = bkg1, r2 = bkg2, vflag = 0.0f;
        if (pf != -1) {
            vflag = 1.0f;
            const int local = pf - b * F;
            const int i0 = face_uv[local * 3 + 0];
            const int i1 = face_uv[local * 3 + 1];
            const int i2 = face_uv[local * 3 + 2];
            const float b0 = bary[(size_t)idx * 3 + 0];
            const float b1 = bary[(size_t)idx * 3 + 1];
            const float b2 = bary[(size_t)idx * 3 + 2];
            const float u = b0 * vertex_uv[i0 * 2] + b1 * vertex_uv[i1 * 2] +
                            b2 * vertex_uv[i2 * 2];
            const float v = b0 * (1.0f - vertex_uv[i0 * 2 + 1]) +
                            b1 * (1.0f - vertex_uv[i1 * 2 + 1]) +
                            b2 * (1.0f - vertex_uv[i2 * 2 + 1]);
            float x = fminf(fmaxf(u * 1023.0f, 0.0f), 1023.0f);
            float y = fminf(fmaxf(v * 1023.0f, 0.0f), 1023.0f);
            const float xf = floorf(x), yf = floorf(y);
            const int x0 = (int)xf, y0 = (int)yf;
            const int x1 = min(x0 + 1, WMASK), y1 = min(y0 + 1, WMASK);
            const float wxx = x - xf, wyy = y - yf;
            const float iwx = 1.0f - wxx, iwy = 1.0f - wyy;
            const float* texb = uvmap + ((size_t)b * 3 << 20);
            float out[3];
            #pragma unroll
            for (int c = 0; c < 3; ++c) {
                const float* t = texb + ((size_t)c << 20);
                const float t00 = t[(y0 << 10) | x0];
                const float t01 = t[(y0 << 10) | x1];
                const float t10 = t[(y1 << 10) | x0];
                const float t11 = t[(y1 << 10) | x1];
                out[c] = (t00 * iwx + t01 * wxx) * iwy + (t10 * iwx + t11 * wxx) * wyy;
            }
            r0 = out[0]; r1 = out[1]; r2 = out[2];
        }
        const size_t ob = (size_t)b * 3 * HWT + hw;
        __builtin_nontemporal_store(r0, &render[ob]);
        __builtin_nontemporal_store(r1, &render[ob + HWT]);
        __builtin_nontemporal_store(r2, &render[ob + 2 * (size_t)HWT]);
        __builtin_nontemporal_store(vflag, &is_valid[idx]);
    }
}

extern "C" void kernel_launch(void* const* d_in, const int* in_sizes, int n_in,
                              void* d_out, int out_size, void* d_ws, size_t ws_size,
                              hipStream_t stream) {
    const float* bary        = (const float*)d_in[0];
    const float* uvmap       = (const float*)d_in[1];
    const float* vertex_uv   = (const float*)d_in[2];
    const float* bkg         = (const float*)d_in[3];
    const int*   pix_to_face = (const int*)d_in[4];
    const int*   face_uv     = (const int*)d_in[5];
    const int F = in_sizes[5] / 3;   // 40000

    float* render   = (float*)d_out;
    float* is_valid = (float*)d_out + (size_t)BB * 3 * HWT;

    const size_t Q32_B  = (size_t)BB * HWT * 32;            // 128 MiB
    const size_t FTAB_B = (size_t)F * 2 * sizeof(float4);   // ~1.25 MiB

    if (ws_size >= Q32_B + FTAB_B) {
        unsigned* ptexu = (unsigned*)d_ws;
        float4*   ftab  = (float4*)((char*)d_ws + Q32_B);
        const int nftab = (F + 255) / 256;
        k_ftab_pack<<<nftab + (BB * HWT) / 256, 256, 0, stream>>>(
            face_uv, vertex_uv, ftab, uvmap, ptexu, F, nftab);
        render_quad<<<HWT / 256, 256, 0, stream>>>(
            ptexu, ftab, bary, pix_to_face, bkg, F, render, is_valid);
    } else {
        uvrender_direct<<<2048, 256, 0, stream>>>(
            bary, uvmap, vertex_uv, bkg, pix_to_face, face_uv, F,
            render, is_valid);
    }
}